// Round 1
// baseline (106.052 us; speedup 1.0000x reference)
//
#include <hip/hip_runtime.h>

// Problem constants (from reference)
#define NN     1024      // nodes
#define INDIM  64
#define EREAL  16384
#define HD     64        // H*D = 8*8

// GAMMA = 0.1 ; C = GAMMA/(1+GAMMA) ; scale = sqrt(D)=sqrt(8)
__constant__ const float C_BASE    = 0.1f / 1.1f;
__constant__ const float INV_1P1   = 1.0f / 1.1f;
__constant__ const float INV_SCALE = 0.35355339059327373f;  // 1/sqrt(8)

// ---- node projections: Qh = h@WQ, Kh = h@WK, Vh = h@WV  (each [1024,64]) ----
__global__ void proj_kernel(const float* __restrict__ h,
                            const float* __restrict__ WQ,
                            const float* __restrict__ WK,
                            const float* __restrict__ WV,
                            float* __restrict__ Qh,
                            float* __restrict__ Kh,
                            float* __restrict__ Vh) {
    __shared__ float hrow[INDIM];
    const int row = blockIdx.x;
    const int t   = threadIdx.x;           // 0..63 = output column
    hrow[t] = h[row * INDIM + t];
    __syncthreads();
    float q = 0.f, k = 0.f, v = 0.f;
#pragma unroll 8
    for (int r = 0; r < INDIM; ++r) {
        const float hv = hrow[r];
        q += hv * WQ[r * HD + t];
        k += hv * WK[r * HD + t];
        v += hv * WV[r * HD + t];
    }
    Qh[row * HD + t] = q;
    Kh[row * HD + t] = k;
    Vh[row * HD + t] = v;
}

// ---- column sums of Vh: S[t] = sum_j Vh[j,t] ----
__global__ void colsum_kernel(const float* __restrict__ Vh, float* __restrict__ S) {
    __shared__ float part[4][HD];
    const int c = threadIdx.x & 63;
    const int p = threadIdx.x >> 6;        // 0..3
    float s = 0.f;
    for (int j = p * 256; j < p * 256 + 256; ++j) s += Vh[j * HD + c];
    part[p][c] = s;
    __syncthreads();
    if (p == 0) S[c] = part[0][c] + part[1][c] + part[2][c] + part[3][c];
}

// ---- dedup: last edge with a given (src,dst) wins (numpy scatter-set semantics) ----
__global__ void winner_kernel(const int* __restrict__ src, const int* __restrict__ dst,
                              int* __restrict__ winner) {
    const int k = blockIdx.x * 256 + threadIdx.x;
    if (k < EREAL) {
        const int key = src[k] * NN + dst[k];
        atomicMax(&winner[key], k + 1);
    }
}

// ---- per-edge delta + scatter-accumulate (one wave of 64 lanes per edge) ----
__global__ void edge_kernel(const float* __restrict__ e,
                            const float* __restrict__ WE,
                            const float* __restrict__ Qh,
                            const float* __restrict__ Kh,
                            const float* __restrict__ Vh,
                            const int* __restrict__ src,
                            const int* __restrict__ dst,
                            const int* __restrict__ winner,
                            float* __restrict__ outacc,
                            float* __restrict__ zacc) {
    const int wid = threadIdx.x >> 6;              // wave id within block (0..3)
    const int k   = blockIdx.x * 4 + wid;          // edge index, uniform per wave
    const int t   = threadIdx.x & 63;              // lane = h*8+d
    const int s = src[k];
    const int d = dst[k];
    // wave-uniform early out: skip dup-losers and self-loops (diag is zeroed anyway)
    if (winner[s * NN + d] != k + 1 || s == d) return;

    // Eh[k, t] = sum_r e[k,r] * WE[r, t]  — broadcast e row via shuffles
    const float ev = e[k * INDIM + t];
    float acc = 0.f;
#pragma unroll
    for (int r = 0; r < INDIM; ++r) {
        acc += __shfl(ev, r, 64) * WE[r * HD + t];
    }
    // wr[h] = sum_d Kh[s,h,d]*Qh[d,h,d]*Eh[h,d] — reduce within each 8-lane head group
    float term = Kh[s * HD + t] * Qh[d * HD + t] * acc;
    term += __shfl_xor(term, 1, 64);
    term += __shfl_xor(term, 2, 64);
    term += __shfl_xor(term, 4, 64);
    const float wr    = fminf(fmaxf(term * INV_SCALE, -5.f), 5.f);
    const float delta = expf(wr) * INV_1P1 - C_BASE;   // real weight minus fake base

    atomicAdd(&outacc[d * HD + t], delta * Vh[s * HD + t]);
    if ((t & 7) == 0) atomicAdd(&zacc[d * 8 + (t >> 3)], delta);
}

// ---- out[j,t] = (C*(S[t]-Vh[j,t]) + outacc[j,t]) / (C*(N-1) + zacc[j,h] + 1e-6) ----
__global__ void finalize_kernel(const float* __restrict__ Vh,
                                const float* __restrict__ S,
                                const float* __restrict__ outacc,
                                const float* __restrict__ zacc,
                                float* __restrict__ out) {
    const int idx = blockIdx.x * 256 + threadIdx.x;    // 0..65535
    const int j = idx >> 6;
    const int t = idx & 63;
    const float z = C_BASE * 1023.f + zacc[j * 8 + (t >> 3)] + 1e-6f;
    const float o = C_BASE * (S[t] - Vh[idx]) + outacc[idx];
    out[idx] = o / z;
}

extern "C" void kernel_launch(void* const* d_in, const int* in_sizes, int n_in,
                              void* d_out, int out_size, void* d_ws, size_t ws_size,
                              hipStream_t stream) {
    const float* h  = (const float*)d_in[0];
    const float* e  = (const float*)d_in[1];
    const float* WQ = (const float*)d_in[2];
    const float* WK = (const float*)d_in[3];
    const float* WE = (const float*)d_in[4];
    // d_in[5..7] = WQ2, WK2, WE2 — provably unused: fake weights are overwritten
    // at every real-edge position and are exactly GAMMA/(1+GAMMA) elsewhere.
    const float* WV = (const float*)d_in[8];
    const int* src  = (const int*)d_in[9];
    const int* dst  = (const int*)d_in[10];
    float* out = (float*)d_out;

    char* ws = (char*)d_ws;
    float* Qh = (float*)(ws + (0 << 10));
    float* Kh = (float*)(ws + (256 << 10));
    float* Vh = (float*)(ws + (512 << 10));
    float* S  = (float*)(ws + (768 << 10));
    // zeroed region (ws is poisoned 0xAA before every timed launch)
    char*  zreg   = ws + (1 << 20);
    float* outacc = (float*)zreg;                  // 256 KB
    float* zacc   = (float*)(zreg + (256 << 10));  // 32 KB
    int*   winner = (int*)(zreg + (288 << 10));    // 4 MB
    const size_t zbytes = (288 << 10) + (4u << 20);

    hipMemsetAsync(zreg, 0, zbytes, stream);
    hipLaunchKernelGGL(proj_kernel,    dim3(NN),   dim3(64),  0, stream, h, WQ, WK, WV, Qh, Kh, Vh);
    hipLaunchKernelGGL(colsum_kernel,  dim3(1),    dim3(256), 0, stream, Vh, S);
    hipLaunchKernelGGL(winner_kernel,  dim3(EREAL / 256), dim3(256), 0, stream, src, dst, winner);
    hipLaunchKernelGGL(edge_kernel,    dim3(EREAL / 4),   dim3(256), 0, stream,
                       e, WE, Qh, Kh, Vh, src, dst, winner, outacc, zacc);
    hipLaunchKernelGGL(finalize_kernel, dim3(NN * HD / 256), dim3(256), 0, stream,
                       Vh, S, outacc, zacc, out);
}